// Round 1
// baseline (248.089 us; speedup 1.0000x reference)
//
#include <hip/hip_runtime.h>
#include <hip/hip_bf16.h>
#include <stdint.h>

typedef __attribute__((ext_vector_type(4))) float f32x4;
typedef __attribute__((ext_vector_type(8))) short short8;
typedef __attribute__((ext_vector_type(4))) unsigned short u16x4;

#define DEV __device__ __forceinline__
#define MFMA16(a, b, c) __builtin_amdgcn_mfma_f32_16x16x32_bf16(a, b, c, 0, 0, 0)

DEV unsigned short f2b(float x) {
  union { float f; uint32_t u; } c; c.f = x;
  uint32_t r = (c.u + 0x7fffu + ((c.u >> 16) & 1u)) >> 16;
  return (unsigned short)r;
}

DEV void gload_lds16(const void* g, void* l) {
  __builtin_amdgcn_global_load_lds((const __attribute__((address_space(1))) void*)g,
                                   (__attribute__((address_space(3))) void*)l, 16, 0, 0);
}

// ---------------- kernel 1: fp32 -> bf16 conversions ----------------
// Xbf (2048x1024), Wbf rows 0..3071 = w_proj, rows 3072..4095 = w_g, Wobf = w_o
__global__ __launch_bounds__(256) void convert_k(
    const float* __restrict__ x, const float* __restrict__ wproj,
    const float* __restrict__ wg, const float* __restrict__ wo,
    unsigned short* __restrict__ Xbf, unsigned short* __restrict__ Wbf,
    unsigned short* __restrict__ Wobf) {
  int i = blockIdx.x * 256 + threadIdx.x;  // one float4 per thread, exact fit
  const float* src; unsigned short* dst;
  if (i < 524288)               { src = x     + (size_t)i * 4;                  dst = Xbf + (size_t)i * 4; }
  else if (i < 524288 + 786432) { int j = i - 524288;            src = wproj + (size_t)j * 4; dst = Wbf + (size_t)j * 4; }
  else if (i < 524288 + 786432 + 262144) { int j = i - (524288 + 786432); src = wg + (size_t)j * 4; dst = Wbf + 3145728 + (size_t)j * 4; }
  else                          { int j = i - (524288 + 786432 + 262144); src = wo + (size_t)j * 4; dst = Wobf + (size_t)j * 4; }
  f32x4 v = *(const f32x4*)src;
  u16x4 o; o.x = f2b(v.x); o.y = f2b(v.y); o.z = f2b(v.z); o.w = f2b(v.w);
  *(u16x4*)dst = o;
}

// ---------------- shared GEMM core: C[128x128] = A[128xK] * B[128xK]^T, K=1024 ----
// m97 structure: BK=32, double-buffered LDS, global_load_lds 16B staging.
DEV void gemm_stage(char* sm, const unsigned short* A, const unsigned short* Bw,
                    int tileMrow, int tileNrow, int buf, int kt, int lane, int wid) {
  const char* gA = (const char*)A;
  const char* gB = (const char*)Bw;
#pragma unroll
  for (int i = 0; i < 2; ++i) {
    int c = wid * 2 + i;                 // chunk 0..7, 1KB each (16 rows x 64B)
    int off = c * 1024 + lane * 16;
    int r = off >> 6, cb = off & 63;
    const char* srcA = gA + ((size_t)(tileMrow + r) * 2048) + kt * 64 + cb;
    gload_lds16(srcA, sm + buf * 8192 + c * 1024);
    const char* srcB = gB + ((size_t)(tileNrow + r) * 2048) + kt * 64 + cb;
    gload_lds16(srcB, sm + 16384 + buf * 8192 + c * 1024);
  }
}

DEV void gemm_main(const unsigned short* A, const unsigned short* Bw,
                   int tileMrow, int tileNrow, f32x4 acc[4][4], char* sm) {
  int tid = threadIdx.x, lane = tid & 63, wid = tid >> 6;
  int wr = wid >> 1, wc = wid & 1;
  gemm_stage(sm, A, Bw, tileMrow, tileNrow, 0, 0, lane, wid);
  for (int kt = 0; kt < 32; ++kt) {
    __syncthreads();  // staging of buf (kt&1) done; prev compute done
    if (kt < 31) gemm_stage(sm, A, Bw, tileMrow, tileNrow, (kt + 1) & 1, kt + 1, lane, wid);
    int ab = (kt & 1) * 8192;
    int rb = (lane & 15) * 64 + ((lane >> 4) * 16);  // row*64B + kgroup*16B
    short8 af[4], bf[4];
#pragma unroll
    for (int mi = 0; mi < 4; ++mi)
      af[mi] = *(const short8*)(sm + ab + (wr * 64 + mi * 16) * 64 + rb);
#pragma unroll
    for (int ni = 0; ni < 4; ++ni)
      bf[ni] = *(const short8*)(sm + 16384 + ab + (wc * 64 + ni * 16) * 64 + rb);
#pragma unroll
    for (int mi = 0; mi < 4; ++mi)
#pragma unroll
      for (int ni = 0; ni < 4; ++ni)
        acc[mi][ni] = MFMA16(af[mi], bf[ni], acc[mi][ni]);
  }
}

// ---------------- kernel 2: QKV+gate projection ----------------
__global__ __launch_bounds__(256) void gemm_qkvg_k(
    const unsigned short* __restrict__ Xbf, const unsigned short* __restrict__ Wbf,
    unsigned short* __restrict__ Qb, unsigned short* __restrict__ Kb,
    unsigned short* __restrict__ Vt, float* __restrict__ G,
    const float* __restrict__ bg) {
  __shared__ char sm[32768];
  int bid = blockIdx.x;
  int swz = (bid & 7) * 64 + (bid >> 3);  // XCD-chunked swizzle, 512 blocks
  int tileM = swz >> 5, tileN = swz & 31;
  f32x4 acc[4][4] = {};
  gemm_main(Xbf, Wbf, tileM * 128, tileN * 128, acc, sm);
  int lane = threadIdx.x & 63, wid = threadIdx.x >> 6;
  int wr = wid >> 1, wc = wid & 1;
#pragma unroll
  for (int mi = 0; mi < 4; ++mi)
#pragma unroll
    for (int ni = 0; ni < 4; ++ni)
#pragma unroll
      for (int j = 0; j < 4; ++j) {
        int row = tileM * 128 + wr * 64 + mi * 16 + ((lane >> 4) << 2) + j;
        int col = tileN * 128 + wc * 64 + ni * 16 + (lane & 15);
        float v = acc[mi][ni][j];
        int b = row >> 10, l = row & 1023;
        if (col < 3072) {
          int h = col / 192, r = col - h * 192;
          size_t base = ((size_t)(b * 16 + h) * 1024 + l) * 64;
          if (r < 64)        Qb[base + r] = f2b(v * 0.125f);
          else if (r < 128)  Kb[base + (r - 64)] = f2b(v);
          else               Vt[((size_t)(b * 16 + h) * 64 + (r - 128)) * 1024 + l] = f2b(v);
        } else {
          int e = col - 3072;
          float s = v + bg[e];
          G[(size_t)row * 1024 + e] = 1.f / (1.f + __expf(-s));
        }
      }
}

// ---------------- kernel 3: attention ----------------
// block = (b, h, 32 q-rows); 4 waves x 256 lk each; S in registers.
// Grid mapping groups all 16 h of one (b,qtile) onto one XCD (bias L2 reuse).
__global__ __launch_bounds__(256) void attn_k(
    const unsigned short* __restrict__ Qb, const unsigned short* __restrict__ Kb,
    const unsigned short* __restrict__ Vt, const float* __restrict__ bias,
    const float* __restrict__ G, unsigned short* __restrict__ Ybf,
    float* __restrict__ outa) {
  __shared__ char sm[50176];
  int tid = threadIdx.x, lane = tid & 63, w = tid >> 6;
  int la = lane & 15, lg = lane >> 4;
  int bid = blockIdx.x;
  int h = (bid >> 3) & 15;
  int slab = ((bid >> 3) >> 4) * 8 + (bid & 7);  // 0..63
  int b = slab >> 5, qt = slab & 31, qbase = qt * 32;
  size_t bh = (size_t)(b * 16 + h);
  const unsigned short* Qh = Qb + bh * 65536;
  const unsigned short* Kh = Kb + bh * 65536;
  const unsigned short* Vh = Vt + bh * 65536;
  const float* biasB = bias + ((size_t)b << 24);
  int lk0 = w * 256;

  short8 qf[2][2];
#pragma unroll
  for (int mi = 0; mi < 2; ++mi)
#pragma unroll
    for (int ks = 0; ks < 2; ++ks)
      qf[mi][ks] = *(const short8*)(Qh + (size_t)(qbase + mi * 16 + la) * 64 + ks * 32 + lg * 8);

  f32x4 acc[2][16] = {};
#pragma unroll
  for (int nf = 0; nf < 16; ++nf) {
    int kb = lk0 + nf * 16;
    const unsigned short* kr = Kh + (size_t)(kb + la) * 64 + lg * 8;
    short8 kf0 = *(const short8*)kr;
    short8 kf1 = *(const short8*)(kr + 32);
    acc[0][nf] = MFMA16(qf[0][0], kf0, acc[0][nf]);
    acc[0][nf] = MFMA16(qf[0][1], kf1, acc[0][nf]);
    acc[1][nf] = MFMA16(qf[1][0], kf0, acc[1][nf]);
    acc[1][nf] = MFMA16(qf[1][1], kf1, acc[1][nf]);
    int lkl = kb + la;
#pragma unroll
    for (int mi = 0; mi < 2; ++mi)
#pragma unroll
      for (int j = 0; j < 4; ++j) {
        int lq = qbase + mi * 16 + lg * 4 + j;
        acc[mi][nf][j] += biasB[((size_t)lq << 14) + ((size_t)lkl << 4) + h];
      }
  }

  // ---- softmax over full row (1024 lk across 4 waves) ----
  float* redm = (float*)(sm + 49152);  // [4][32]
  float* reds = (float*)(sm + 49664);  // [4][32]
  float rmax[2][4];
#pragma unroll
  for (int mi = 0; mi < 2; ++mi)
#pragma unroll
    for (int j = 0; j < 4; ++j) {
      float m = acc[mi][0][j];
#pragma unroll
      for (int nf = 1; nf < 16; ++nf) m = fmaxf(m, acc[mi][nf][j]);
#pragma unroll
      for (int d = 1; d < 16; d <<= 1) m = fmaxf(m, __shfl_xor(m, d));
      rmax[mi][j] = m;
    }
  if (la == 0) {
#pragma unroll
    for (int mi = 0; mi < 2; ++mi)
#pragma unroll
      for (int j = 0; j < 4; ++j) redm[w * 32 + mi * 16 + lg * 4 + j] = rmax[mi][j];
  }
  __syncthreads();
  float rsum[2][4];
#pragma unroll
  for (int mi = 0; mi < 2; ++mi)
#pragma unroll
    for (int j = 0; j < 4; ++j) {
      int r = mi * 16 + lg * 4 + j;
      float m = fmaxf(fmaxf(redm[r], redm[32 + r]), fmaxf(redm[64 + r], redm[96 + r]));
      float s = 0.f;
#pragma unroll
      for (int nf = 0; nf < 16; ++nf) {
        float e = __expf(acc[mi][nf][j] - m);
        acc[mi][nf][j] = e;
        s += e;
      }
#pragma unroll
      for (int d = 1; d < 16; d <<= 1) s += __shfl_xor(s, d);
      rsum[mi][j] = s;
    }
  if (la == 0) {
#pragma unroll
    for (int mi = 0; mi < 2; ++mi)
#pragma unroll
      for (int j = 0; j < 4; ++j) reds[w * 32 + mi * 16 + lg * 4 + j] = rsum[mi][j];
  }
  __syncthreads();
  float rinv[2][4];
#pragma unroll
  for (int mi = 0; mi < 2; ++mi)
#pragma unroll
    for (int j = 0; j < 4; ++j) {
      int r = mi * 16 + lg * 4 + j;
      rinv[mi][j] = 1.f / (reds[r] + reds[32 + r] + reds[64 + r] + reds[96 + r]);
    }

  // ---- per-wave: write probs (transposed, coalesced) + PV, in 64-lk chunks ----
  char* pb = sm + w * 4096;            // [32][64] bf16, XOR-swizzled rows
  char* ot = sm + 16384 + w * 8192;    // [64][32] f32, XOR-swizzled
  f32x4 yacc[2][4] = {};
#pragma unroll
  for (int cc = 0; cc < 4; ++cc) {
#pragma unroll
    for (int mi = 0; mi < 2; ++mi)
#pragma unroll
      for (int nfl = 0; nfl < 4; ++nfl)
#pragma unroll
        for (int j = 0; j < 4; ++j) {
          int nf = cc * 4 + nfl;
          float v = acc[mi][nf][j] * rinv[mi][j];
          int lqL = mi * 16 + lg * 4 + j;
          int lkL = nfl * 16 + la;
          *(unsigned short*)(pb + ((lqL * 128 + lkL * 2) ^ ((lqL & 7) << 4))) = f2b(v);
          *(float*)(ot + (lkL * 32 + (lqL ^ ((lkL & 7) << 2))) * 4) = v;
        }
    // transposed prob stores: out[b][lk][h][qbase..qbase+32)
#pragma unroll
    for (int it = 0; it < 8; ++it) {
      int idx = it * 64 + lane;
      int lkL = idx >> 3, q4 = idx & 7;
      f32x4 ov = *(const f32x4*)(ot + (lkL * 32 + ((q4 * 4) ^ ((lkL & 7) << 2))) * 4);
      size_t lkG = (size_t)(lk0 + cc * 64 + lkL);
      *(f32x4*)(outa + ((((size_t)b * 1024 + lkG) * 16 + h) * 1024 + qbase + q4 * 4)) = ov;
    }
    // PV for this chunk
#pragma unroll
    for (int ks = 0; ks < 2; ++ks) {
      short8 pa[2];
#pragma unroll
      for (int mi = 0; mi < 2; ++mi) {
        int row = mi * 16 + la;
        pa[mi] = *(const short8*)(pb + ((row * 128 + (ks * 32 + lg * 8) * 2) ^ ((row & 7) << 4)));
      }
#pragma unroll
      for (int ni = 0; ni < 4; ++ni) {
        short8 vf = *(const short8*)(Vh + (size_t)(ni * 16 + la) * 1024 + lk0 + cc * 64 + ks * 32 + lg * 8);
        yacc[0][ni] = MFMA16(pa[0], vf, yacc[0][ni]);
        yacc[1][ni] = MFMA16(pa[1], vf, yacc[1][ni]);
      }
    }
  }

  // ---- cross-wave y reduction + gate, write Ybf (bf16) ----
#pragma unroll
  for (int mi = 0; mi < 2; ++mi)
#pragma unroll
    for (int ni = 0; ni < 4; ++ni)
#pragma unroll
      for (int j = 0; j < 4; ++j) {
        int lqL = mi * 16 + lg * 4 + j, c = ni * 16 + la;
        *(float*)(sm + 16384 + w * 8192 + (lqL * 64 + c) * 4) = yacc[mi][ni][j];
      }
  __syncthreads();
#pragma unroll
  for (int rr = 0; rr < 8; ++rr) {
    int e = rr * 256 + tid;
    int lqL = e >> 6, c = e & 63;
    float s = 0.f;
#pragma unroll
    for (int w4 = 0; w4 < 4; ++w4) s += *(const float*)(sm + 16384 + w4 * 8192 + e * 4);
    size_t grow = (size_t)b * 1024 + qbase + lqL;
    size_t gi = grow * 1024 + h * 64 + c;
    Ybf[gi] = f2b(s * G[gi]);
  }
}

// ---------------- kernel 4: output projection ----------------
__global__ __launch_bounds__(256) void gemm_out_k(
    const unsigned short* __restrict__ Ybf, const unsigned short* __restrict__ Wobf,
    const float* __restrict__ bo, float* __restrict__ outy) {
  __shared__ char sm[32768];
  int bid = blockIdx.x;
  int swz = (bid & 7) * 16 + (bid >> 3);  // 128 blocks
  int tileM = swz >> 3, tileN = swz & 7;
  f32x4 acc[4][4] = {};
  gemm_main(Ybf, Wobf, tileM * 128, tileN * 128, acc, sm);
  int lane = threadIdx.x & 63, wid = threadIdx.x >> 6;
  int wr = wid >> 1, wc = wid & 1;
#pragma unroll
  for (int mi = 0; mi < 4; ++mi)
#pragma unroll
    for (int ni = 0; ni < 4; ++ni)
#pragma unroll
      for (int j = 0; j < 4; ++j) {
        int row = tileM * 128 + wr * 64 + mi * 16 + ((lane >> 4) << 2) + j;
        int col = tileN * 128 + wc * 64 + ni * 16 + (lane & 15);
        outy[(size_t)row * 1024 + col] = acc[mi][ni][j] + bo[col];
      }
}

extern "C" void kernel_launch(void* const* d_in, const int* in_sizes, int n_in,
                              void* d_out, int out_size, void* d_ws, size_t ws_size,
                              hipStream_t stream) {
  const float* x     = (const float*)d_in[0];
  const float* bias  = (const float*)d_in[1];
  const float* wproj = (const float*)d_in[2];
  const float* wo    = (const float*)d_in[3];
  const float* bo    = (const float*)d_in[4];
  const float* wg    = (const float*)d_in[5];
  const float* bg    = (const float*)d_in[6];
  float* outy = (float*)d_out;
  float* outa = outy + 2097152;  // 2*1024*1024 y elems, then attn (B,Lk,H,Lq)

  char* ws = (char*)d_ws;
  unsigned short* Xbf  = (unsigned short*)(ws);
  unsigned short* Wbf  = (unsigned short*)(ws + 4  * 1024 * 1024);
  unsigned short* Wobf = (unsigned short*)(ws + 12 * 1024 * 1024);
  unsigned short* Qb   = (unsigned short*)(ws + 14 * 1024 * 1024);
  unsigned short* Kb   = (unsigned short*)(ws + 18 * 1024 * 1024);
  unsigned short* Vt   = (unsigned short*)(ws + 22 * 1024 * 1024);
  float*          G    = (float*)        (ws + 26 * 1024 * 1024);
  unsigned short* Ybf  = (unsigned short*)(ws + 34 * 1024 * 1024);
  if (ws_size < (size_t)38 * 1024 * 1024) return;  // need 38MB scratch

  convert_k<<<dim3(7168), dim3(256), 0, stream>>>(x, wproj, wg, wo, Xbf, Wbf, Wobf);
  gemm_qkvg_k<<<dim3(512), dim3(256), 0, stream>>>(Xbf, Wbf, Qb, Kb, Vt, G, bg);
  attn_k<<<dim3(1024), dim3(256), 0, stream>>>(Qb, Kb, Vt, bias, G, Ybf, outa);
  gemm_out_k<<<dim3(128), dim3(256), 0, stream>>>(Ybf, Wobf, bo, outy);
}

// Round 2
// 212.591 us; speedup vs baseline: 1.1670x; 1.1670x over previous
//
#include <hip/hip_runtime.h>
#include <hip/hip_bf16.h>
#include <stdint.h>

typedef __attribute__((ext_vector_type(4))) float f32x4;
typedef __attribute__((ext_vector_type(8))) short short8;
typedef __attribute__((ext_vector_type(4))) unsigned short u16x4;

#define DEV __device__ __forceinline__
#define MFMA16(a, b, c) __builtin_amdgcn_mfma_f32_16x16x32_bf16(a, b, c, 0, 0, 0)

DEV unsigned short f2b(float x) {
  union { float f; uint32_t u; } c; c.f = x;
  uint32_t r = (c.u + 0x7fffu + ((c.u >> 16) & 1u)) >> 16;
  return (unsigned short)r;
}

DEV void gload_lds16(const void* g, void* l) {
  __builtin_amdgcn_global_load_lds((const __attribute__((address_space(1))) void*)g,
                                   (__attribute__((address_space(3))) void*)l, 16, 0, 0);
}

// ---------------- kernel 1: fp32->bf16 converts + bias transpose ----------------
// blocks [0,7168): convert x/w_proj/w_g/w_o to bf16
// blocks [7168,15360): transpose bias (2,1M,16) -> biasT (2,16,1M) fp32
__global__ __launch_bounds__(256) void prep_k(
    const float* __restrict__ x, const float* __restrict__ wproj,
    const float* __restrict__ wg, const float* __restrict__ wo,
    const float* __restrict__ bias,
    unsigned short* __restrict__ Xbf, unsigned short* __restrict__ Wbf,
    unsigned short* __restrict__ Wobf, float* __restrict__ biasT) {
  __shared__ float tt[256 * 17];
  int bid = blockIdx.x, tid = threadIdx.x;
  if (bid < 7168) {
    int i = bid * 256 + tid;  // one float4 per thread, exact fit
    const float* src; unsigned short* dst;
    if (i < 524288)               { src = x     + (size_t)i * 4;                  dst = Xbf + (size_t)i * 4; }
    else if (i < 524288 + 786432) { int j = i - 524288;            src = wproj + (size_t)j * 4; dst = Wbf + (size_t)j * 4; }
    else if (i < 524288 + 786432 + 262144) { int j = i - (524288 + 786432); src = wg + (size_t)j * 4; dst = Wbf + 3145728 + (size_t)j * 4; }
    else                          { int j = i - (524288 + 786432 + 262144); src = wo + (size_t)j * 4; dst = Wobf + (size_t)j * 4; }
    f32x4 v = *(const f32x4*)src;
    u16x4 o; o.x = f2b(v.x); o.y = f2b(v.y); o.z = f2b(v.z); o.w = f2b(v.w);
    *(u16x4*)dst = o;
  } else {
    int tb = bid - 7168;                    // 0..8191
    int b = tb >> 12, n0 = (tb & 4095) << 8;
    const float* src = bias + ((size_t)b << 24) + ((size_t)n0 << 4);
#pragma unroll
    for (int l = 0; l < 4; ++l) {
      int idx = l * 256 + tid;              // float4 index in 256x16 tile
      f32x4 v = ((const f32x4*)src)[idx];
      int n = idx >> 2, h0 = (idx & 3) * 4;
#pragma unroll
      for (int i = 0; i < 4; ++i) tt[n * 17 + h0 + i] = v[i];
    }
    __syncthreads();
    int h = tid >> 4, q = tid & 15;
    float* dst = biasT + ((size_t)b << 24) + ((size_t)h << 20) + n0;
#pragma unroll
    for (int r = 0; r < 4; ++r) {
      int n = (r * 16 + q) * 4;
      f32x4 o;
#pragma unroll
      for (int i = 0; i < 4; ++i) o[i] = tt[(n + i) * 17 + h];
      *(f32x4*)(dst + n) = o;
    }
  }
}

// ---------------- shared GEMM core: C[128x128] = A[128xK] * B[128xK]^T, K=1024 ----
DEV void gemm_stage(char* sm, const unsigned short* A, const unsigned short* Bw,
                    int tileMrow, int tileNrow, int buf, int kt, int lane, int wid) {
  const char* gA = (const char*)A;
  const char* gB = (const char*)Bw;
#pragma unroll
  for (int i = 0; i < 2; ++i) {
    int c = wid * 2 + i;                 // chunk 0..7, 1KB each (16 rows x 64B)
    int off = c * 1024 + lane * 16;
    int r = off >> 6, cb = off & 63;
    const char* srcA = gA + ((size_t)(tileMrow + r) * 2048) + kt * 64 + cb;
    gload_lds16(srcA, sm + buf * 8192 + c * 1024);
    const char* srcB = gB + ((size_t)(tileNrow + r) * 2048) + kt * 64 + cb;
    gload_lds16(srcB, sm + 16384 + buf * 8192 + c * 1024);
  }
}

DEV void gemm_main(const unsigned short* A, const unsigned short* Bw,
                   int tileMrow, int tileNrow, f32x4 acc[4][4], char* sm) {
  int tid = threadIdx.x, lane = tid & 63, wid = tid >> 6;
  int wr = wid >> 1, wc = wid & 1;
  gemm_stage(sm, A, Bw, tileMrow, tileNrow, 0, 0, lane, wid);
  for (int kt = 0; kt < 32; ++kt) {
    __syncthreads();
    if (kt < 31) gemm_stage(sm, A, Bw, tileMrow, tileNrow, (kt + 1) & 1, kt + 1, lane, wid);
    int ab = (kt & 1) * 8192;
    int rb = (lane & 15) * 64 + ((lane >> 4) * 16);
    short8 af[4], bf[4];
#pragma unroll
    for (int mi = 0; mi < 4; ++mi)
      af[mi] = *(const short8*)(sm + ab + (wr * 64 + mi * 16) * 64 + rb);
#pragma unroll
    for (int ni = 0; ni < 4; ++ni)
      bf[ni] = *(const short8*)(sm + 16384 + ab + (wc * 64 + ni * 16) * 64 + rb);
#pragma unroll
    for (int mi = 0; mi < 4; ++mi)
#pragma unroll
      for (int ni = 0; ni < 4; ++ni)
        acc[mi][ni] = MFMA16(af[mi], bf[ni], acc[mi][ni]);
  }
}

// ---------------- kernel 2: QKV+gate projection ----------------
__global__ __launch_bounds__(256) void gemm_qkvg_k(
    const unsigned short* __restrict__ Xbf, const unsigned short* __restrict__ Wbf,
    unsigned short* __restrict__ Qb, unsigned short* __restrict__ Kb,
    unsigned short* __restrict__ Vt, float* __restrict__ G,
    const float* __restrict__ bg) {
  __shared__ char sm[32768];
  int bid = blockIdx.x;
  int swz = (bid & 7) * 64 + (bid >> 3);  // XCD-chunked swizzle, 512 blocks
  int tileM = swz >> 5, tileN = swz & 31;
  f32x4 acc[4][4] = {};
  gemm_main(Xbf, Wbf, tileM * 128, tileN * 128, acc, sm);
  int lane = threadIdx.x & 63, wid = threadIdx.x >> 6;
  int wr = wid >> 1, wc = wid & 1;
#pragma unroll
  for (int mi = 0; mi < 4; ++mi)
#pragma unroll
    for (int ni = 0; ni < 4; ++ni)
#pragma unroll
      for (int j = 0; j < 4; ++j) {
        int row = tileM * 128 + wr * 64 + mi * 16 + ((lane >> 4) << 2) + j;
        int col = tileN * 128 + wc * 64 + ni * 16 + (lane & 15);
        float v = acc[mi][ni][j];
        int b = row >> 10, l = row & 1023;
        if (col < 3072) {
          int h = col / 192, r = col - h * 192;
          size_t base = ((size_t)(b * 16 + h) * 1024 + l) * 64;
          if (r < 64)        Qb[base + r] = f2b(v * 0.125f);
          else if (r < 128)  Kb[base + (r - 64)] = f2b(v);
          else               Vt[((size_t)(b * 16 + h) * 64 + (r - 128)) * 1024 + l] = f2b(v);
        } else {
          int e = col - 3072;
          float s = v + bg[e];
          G[(size_t)row * 1024 + e] = 1.f / (1.f + __expf(-s));
        }
      }
}

// ---------------- kernel 3: attention ----------------
// BT=1: B_ is biasT (B,H,Lq,Lk) — coalesced loads. BT=0: original (B,Lq,Lk,H).
template <int BT>
__global__ __launch_bounds__(256) void attn_k(
    const unsigned short* __restrict__ Qb, const unsigned short* __restrict__ Kb,
    const unsigned short* __restrict__ Vt, const float* __restrict__ B_,
    const float* __restrict__ G, unsigned short* __restrict__ Ybf,
    float* __restrict__ outa) {
  __shared__ char sm[51200];
  int tid = threadIdx.x, lane = tid & 63, w = tid >> 6;
  int la = lane & 15, lg = lane >> 4;
  int bid = blockIdx.x;
  int h = (bid >> 3) & 15;
  int slab = ((bid >> 3) >> 4) * 8 + (bid & 7);  // 0..63
  int b = slab >> 5, qt = slab & 31, qbase = qt * 32;
  size_t bh = (size_t)(b * 16 + h);
  const unsigned short* Qh = Qb + bh * 65536;
  const unsigned short* Kh = Kb + bh * 65536;
  const unsigned short* Vh = Vt + bh * 65536;
  const float* biasB = B_ + (BT ? (bh << 20) : ((size_t)b << 24));
  int lk0 = w * 256;

  short8 qf[2][2];
#pragma unroll
  for (int mi = 0; mi < 2; ++mi)
#pragma unroll
    for (int ks = 0; ks < 2; ++ks)
      qf[mi][ks] = *(const short8*)(Qh + (size_t)(qbase + mi * 16 + la) * 64 + ks * 32 + lg * 8);

  f32x4 acc[2][16] = {};
#pragma unroll
  for (int nf = 0; nf < 16; ++nf) {
    int kb = lk0 + nf * 16;
    const unsigned short* kr = Kh + (size_t)(kb + la) * 64 + lg * 8;
    short8 kf0 = *(const short8*)kr;
    short8 kf1 = *(const short8*)(kr + 32);
    acc[0][nf] = MFMA16(qf[0][0], kf0, acc[0][nf]);
    acc[0][nf] = MFMA16(qf[0][1], kf1, acc[0][nf]);
    acc[1][nf] = MFMA16(qf[1][0], kf0, acc[1][nf]);
    acc[1][nf] = MFMA16(qf[1][1], kf1, acc[1][nf]);
    int lkl = kb + la;
#pragma unroll
    for (int mi = 0; mi < 2; ++mi)
#pragma unroll
      for (int j = 0; j < 4; ++j) {
        int lq = qbase + mi * 16 + lg * 4 + j;
        if (BT) acc[mi][nf][j] += biasB[((size_t)lq << 10) + lkl];
        else    acc[mi][nf][j] += biasB[((size_t)lq << 14) + ((size_t)lkl << 4) + h];
      }
  }

  // ---- softmax over full row (1024 lk across 4 waves) ----
  float* redm = (float*)(sm + 50176);  // [4][32]
  float* reds = (float*)(sm + 50688);  // [4][32]
  float rmax[2][4];
#pragma unroll
  for (int mi = 0; mi < 2; ++mi)
#pragma unroll
    for (int j = 0; j < 4; ++j) {
      float m = acc[mi][0][j];
#pragma unroll
      for (int nf = 1; nf < 16; ++nf) m = fmaxf(m, acc[mi][nf][j]);
#pragma unroll
      for (int d = 1; d < 16; d <<= 1) m = fmaxf(m, __shfl_xor(m, d));
      rmax[mi][j] = m;
    }
  if (la == 0) {
#pragma unroll
    for (int mi = 0; mi < 2; ++mi)
#pragma unroll
      for (int j = 0; j < 4; ++j) redm[w * 32 + mi * 16 + lg * 4 + j] = rmax[mi][j];
  }
  __syncthreads();
  float rsum[2][4];
#pragma unroll
  for (int mi = 0; mi < 2; ++mi)
#pragma unroll
    for (int j = 0; j < 4; ++j) {
      int r = mi * 16 + lg * 4 + j;
      float m = fmaxf(fmaxf(redm[r], redm[32 + r]), fmaxf(redm[64 + r], redm[96 + r]));
      float s = 0.f;
#pragma unroll
      for (int nf = 0; nf < 16; ++nf) {
        float e = __expf(acc[mi][nf][j] - m);
        acc[mi][nf][j] = e;
        s += e;
      }
#pragma unroll
      for (int d = 1; d < 16; d <<= 1) s += __shfl_xor(s, d);
      rsum[mi][j] = s;
    }
  if (la == 0) {
#pragma unroll
    for (int mi = 0; mi < 2; ++mi)
#pragma unroll
      for (int j = 0; j < 4; ++j) reds[w * 32 + mi * 16 + lg * 4 + j] = rsum[mi][j];
  }
  __syncthreads();
  float rinv[2][4];
#pragma unroll
  for (int mi = 0; mi < 2; ++mi)
#pragma unroll
    for (int j = 0; j < 4; ++j) {
      int r = mi * 16 + lg * 4 + j;
      rinv[mi][j] = 1.f / (reds[r] + reds[32 + r] + reds[64 + r] + reds[96 + r]);
    }

  // ---- per-wave: write probs (transposed, coalesced) + PV, in 64-lk chunks ----
  char* pb = sm + w * 4096;                      // [32][64] bf16, XOR-swizzled rows
  float* ot = (float*)(sm + 16384 + w * 8448);   // [64][33] f32 (pad-33)
  f32x4 yacc[2][4] = {};
#pragma unroll
  for (int cc = 0; cc < 4; ++cc) {
#pragma unroll
    for (int mi = 0; mi < 2; ++mi)
#pragma unroll
      for (int nfl = 0; nfl < 4; ++nfl)
#pragma unroll
        for (int j = 0; j < 4; ++j) {
          int nf = cc * 4 + nfl;
          float v = acc[mi][nf][j] * rinv[mi][j];
          int lqL = mi * 16 + lg * 4 + j;
          int lkL = nfl * 16 + la;
          *(unsigned short*)(pb + ((lqL * 128 + lkL * 2) ^ ((lqL & 7) << 4))) = f2b(v);
          ot[lkL * 33 + lqL] = v;
        }
    // transposed prob stores: out[b][lk][h][qbase..qbase+32)
#pragma unroll
    for (int it = 0; it < 8; ++it) {
      int idx = it * 64 + lane;
      int lkL = idx >> 3, q4 = idx & 7;
      f32x4 ov;
#pragma unroll
      for (int i = 0; i < 4; ++i) ov[i] = ot[lkL * 33 + q4 * 4 + i];
      size_t lkG = (size_t)(lk0 + cc * 64 + lkL);
      *(f32x4*)(outa + ((((size_t)b * 1024 + lkG) * 16 + h) * 1024 + qbase + q4 * 4)) = ov;
    }
    // PV for this chunk
#pragma unroll
    for (int ks = 0; ks < 2; ++ks) {
      short8 pa[2];
#pragma unroll
      for (int mi = 0; mi < 2; ++mi) {
        int row = mi * 16 + la;
        pa[mi] = *(const short8*)(pb + ((row * 128 + (ks * 32 + lg * 8) * 2) ^ ((row & 7) << 4)));
      }
#pragma unroll
      for (int ni = 0; ni < 4; ++ni) {
        short8 vf = *(const short8*)(Vh + (size_t)(ni * 16 + la) * 1024 + lk0 + cc * 64 + ks * 32 + lg * 8);
        yacc[0][ni] = MFMA16(pa[0], vf, yacc[0][ni]);
        yacc[1][ni] = MFMA16(pa[1], vf, yacc[1][ni]);
      }
    }
  }

  // ---- cross-wave y reduction + gate, write Ybf (bf16) ----
  __syncthreads();  // ot reads done before overwrite
#pragma unroll
  for (int mi = 0; mi < 2; ++mi)
#pragma unroll
    for (int ni = 0; ni < 4; ++ni)
#pragma unroll
      for (int j = 0; j < 4; ++j) {
        int lqL = mi * 16 + lg * 4 + j, c = ni * 16 + la;
        *(float*)(sm + 16384 + w * 8448 + (lqL * 64 + c) * 4) = yacc[mi][ni][j];
      }
  __syncthreads();
#pragma unroll
  for (int rr = 0; rr < 8; ++rr) {
    int e = rr * 256 + tid;
    int lqL = e >> 6, c = e & 63;
    float s = 0.f;
#pragma unroll
    for (int w4 = 0; w4 < 4; ++w4) s += *(const float*)(sm + 16384 + w4 * 8448 + e * 4);
    size_t grow = (size_t)b * 1024 + qbase + lqL;
    size_t gi = grow * 1024 + h * 64 + c;
    Ybf[gi] = f2b(s * G[gi]);
  }
}

// ---------------- kernel 4: output projection ----------------
__global__ __launch_bounds__(256) void gemm_out_k(
    const unsigned short* __restrict__ Ybf, const unsigned short* __restrict__ Wobf,
    const float* __restrict__ bo, float* __restrict__ outy) {
  __shared__ char sm[32768];
  int bid = blockIdx.x;
  int swz = (bid & 7) * 16 + (bid >> 3);  // 128 blocks
  int tileM = swz >> 3, tileN = swz & 7;
  f32x4 acc[4][4] = {};
  gemm_main(Ybf, Wobf, tileM * 128, tileN * 128, acc, sm);
  int lane = threadIdx.x & 63, wid = threadIdx.x >> 6;
  int wr = wid >> 1, wc = wid & 1;
#pragma unroll
  for (int mi = 0; mi < 4; ++mi)
#pragma unroll
    for (int ni = 0; ni < 4; ++ni)
#pragma unroll
      for (int j = 0; j < 4; ++j) {
        int row = tileM * 128 + wr * 64 + mi * 16 + ((lane >> 4) << 2) + j;
        int col = tileN * 128 + wc * 64 + ni * 16 + (lane & 15);
        outy[(size_t)row * 1024 + col] = acc[mi][ni][j] + bo[col];
      }
}

extern "C" void kernel_launch(void* const* d_in, const int* in_sizes, int n_in,
                              void* d_out, int out_size, void* d_ws, size_t ws_size,
                              hipStream_t stream) {
  const float* x     = (const float*)d_in[0];
  const float* bias  = (const float*)d_in[1];
  const float* wproj = (const float*)d_in[2];
  const float* wo    = (const float*)d_in[3];
  const float* bo    = (const float*)d_in[4];
  const float* wg    = (const float*)d_in[5];
  const float* bg    = (const float*)d_in[6];
  float* outy = (float*)d_out;
  float* outa = outy + 2097152;  // y (2M floats), then attn (B,Lk,H,Lq)

  char* ws = (char*)d_ws;
  unsigned short* Xbf  = (unsigned short*)(ws);
  unsigned short* Wbf  = (unsigned short*)(ws + 4  * 1024 * 1024);
  unsigned short* Wobf = (unsigned short*)(ws + 12 * 1024 * 1024);
  unsigned short* Qb   = (unsigned short*)(ws + 14 * 1024 * 1024);
  unsigned short* Kb   = (unsigned short*)(ws + 18 * 1024 * 1024);
  unsigned short* Vt   = (unsigned short*)(ws + 22 * 1024 * 1024);
  float*          G    = (float*)        (ws + 26 * 1024 * 1024);
  unsigned short* Ybf  = (unsigned short*)(ws + 34 * 1024 * 1024);
  float*          biasT= (float*)        (ws + (size_t)38 * 1024 * 1024);
  if (ws_size < (size_t)38 * 1024 * 1024) return;
  bool big = ws_size >= (size_t)167 * 1024 * 1024;  // 38MB + 128MB biasT + slack

  prep_k<<<dim3(big ? 15360 : 7168), dim3(256), 0, stream>>>(
      x, wproj, wg, wo, bias, Xbf, Wbf, Wobf, biasT);
  gemm_qkvg_k<<<dim3(512), dim3(256), 0, stream>>>(Xbf, Wbf, Qb, Kb, Vt, G, bg);
  if (big) attn_k<1><<<dim3(1024), dim3(256), 0, stream>>>(Qb, Kb, Vt, biasT, G, Ybf, outa);
  else     attn_k<0><<<dim3(1024), dim3(256), 0, stream>>>(Qb, Kb, Vt, bias,  G, Ybf, outa);
  gemm_out_k<<<dim3(128), dim3(256), 0, stream>>>(Ybf, Wobf, bo, outy);
}